// Round 7
// baseline (3893.007 us; speedup 1.0000x reference)
//
#include <hip/hip_runtime.h>
#include <hip/hip_bf16.h>

typedef short short8 __attribute__((ext_vector_type(8)));
typedef short short4v __attribute__((ext_vector_type(4)));
typedef float f32x4 __attribute__((ext_vector_type(4)));
typedef float float4g __attribute__((ext_vector_type(4)));
typedef unsigned int uint2v __attribute__((ext_vector_type(2)));
typedef __fp16 half4 __attribute__((ext_vector_type(4)));
typedef unsigned short ushort;

#define LOG2E 1.44269504088896f
#define GB_OFF 46080   // gate-exchange buffer (16384 B)
#define WO_OFF 62464   // Wo fragments (2048 B)

__device__ __forceinline__ ushort f2bf_fast(float f) {
  unsigned u = __builtin_bit_cast(unsigned, f);
  return (ushort)((u + 0x8000u) >> 16);
}
template <int BM>
__device__ __forceinline__ float pkmerge(float oldv, float srcv) {
  int o = __builtin_bit_cast(int, oldv);
  int s = __builtin_bit_cast(int, srcv);
  int r = __builtin_amdgcn_update_dpp(o, s, 0x128 /*row_ror:8*/, 0xF, BM, false);
  return __builtin_bit_cast(float, r);
}
__device__ __forceinline__ void barrier_lgkm() {
  asm volatile("s_waitcnt lgkmcnt(0)\n\ts_barrier" ::: "memory");
}
__device__ __forceinline__ unsigned pk16(float a, float b) {
  auto r = __builtin_amdgcn_cvt_pkrtz(a, b);  // __fp16 ext_vector(2)
  return __builtin_bit_cast(unsigned, r);
}

// ---------------- prep: weights -> bf16 MFMA B-frag blocks, 16 wave-slots ----------------
// wfrag: [wslot(16)][l(4)][kc(4)][lane(64)][8 bf16]; wslot: role=(w>>2)&1 (0:[i|f] 1:[g|o]),
// ws=(w&3)|((w>>3)<<2) -> hcols ws*8..+8. l=0 K<64 holds Wx=Wih0@Wo (pred folded), bias +Wih0@bo;
// t0 bias set: b + Wih0@x0.
__global__ void prep_kernel(const float* __restrict__ Wih0, const float* __restrict__ Wihr,
                            const float* __restrict__ Whh, const float* __restrict__ bih,
                            const float* __restrict__ bhh, const float* __restrict__ Wo,
                            const float* __restrict__ bo,
                            ushort* __restrict__ wfrag, ushort* __restrict__ wofrag,
                            float* __restrict__ bsum, float* __restrict__ bsum_t0) {
  int id = blockIdx.x * 256 + threadIdx.x;
  if (id < 131072) {
    int j = id & 7, lane = (id >> 3) & 63, kc = (id >> 9) & 3, l = (id >> 11) & 3,
        wslot = id >> 13;
    int role = (wslot >> 2) & 1, ws = (wslot & 3) | ((wslot >> 3) << 2);
    int c16 = lane & 15, qq = lane >> 4;
    int gate = role * 2 + (c16 >= 8 ? 1 : 0);
    int n = gate * 64 + ws * 8 + (c16 & 7);
    int k = kc * 32 + qq * 8 + j;
    float v;
    if (k < 64) {
      if (l == 0)
        v = Wih0[n * 3 + 0] * Wo[k] + Wih0[n * 3 + 1] * Wo[64 + k] +
            Wih0[n * 3 + 2] * Wo[128 + k];
      else
        v = Wihr[((l - 1) * 256 + n) * 64 + k];
    } else {
      v = Whh[(l * 256 + n) * 64 + (k - 64)];
    }
    wfrag[id] = f2bf_fast(v);
  } else if (id < 132096) {
    int id2 = id - 131072;
    int j = id2 & 7, lane = (id2 >> 3) & 63, kc = id2 >> 9;
    int c16 = lane & 15, qq = lane >> 4;
    int k = kc * 32 + qq * 8 + j;
    float v = (c16 < 3) ? Wo[c16 * 64 + k] : 0.0f;
    wofrag[id2] = f2bf_fast(v);
  } else if (id < 133120) {
    int n2 = id - 132096;
    float v = bih[n2] + bhh[n2];
    if (n2 < 256)
      v += Wih0[n2 * 3 + 0] * bo[0] + Wih0[n2 * 3 + 1] * bo[1] + Wih0[n2 * 3 + 2] * bo[2];
    bsum[n2] = v;
  } else if (id < 133376) {
    int n = id - 133120;
    bsum_t0[n] = bih[n] + bhh[n] + 0.5f * (Wih0[n * 3 + 0] + Wih0[n * 3 + 1]);
  }
}

// rec-half MFMAs, acc init = bias splat (bias rides through MFMA C)
#define RECB(accv, mt, hcN, bN, LN)                                                   \
  {                                                                                   \
    const int arow = (mt) * 16 + c16;                                                 \
    short8 a2 = *(const short8*)((hcN) + arow * 72 + qs8);                            \
    short8 a3 = *(const short8*)((hcN) + arow * 72 + 32 + qs8);                       \
    f32x4 A = {bN, bN, bN, bN};                                                       \
    A = __builtin_amdgcn_mfma_f32_16x16x32_bf16(a2, wreg[LN][2], A, 0, 0, 0);         \
    A = __builtin_amdgcn_mfma_f32_16x16x32_bf16(a3, wreg[LN][3], A, 0, 0, 0);         \
    accv = A;                                                                         \
  }
// input-half MFMAs (accumulate)
#define INB(accv, mt, hpp, LN)                                                        \
  {                                                                                   \
    const int arow = (mt) * 16 + c16;                                                 \
    short8 a0 = *(const short8*)((hpp) + arow * 72 + qs8);                            \
    short8 a1 = *(const short8*)((hpp) + arow * 72 + 32 + qs8);                       \
    accv = __builtin_amdgcn_mfma_f32_16x16x32_bf16(a0, wreg[LN][0], accv, 0, 0, 0);   \
    accv = __builtin_amdgcn_mfma_f32_16x16x32_bf16(a1, wreg[LN][1], accv, 0, 0, 0);   \
  }

// ---------------- main persistent LSTM kernel ----------------
// 16 waves (1024 thr), 64 rows/block. Wave = 1 gate-pair tile x 4 layers (64 weight regs)
// -> <=128 total regs -> 4 waves/SIMD. IF waves ([i|f]) act rows 0-31, GO ([g|o]) rows
// 32-63; gates exchanged via fp16 LDS buffer. Biases folded into acc init. Rec-MFMAs of
// step k+1 issued inside step k's act window. 2 lgkm-only barriers per layer-step.
__global__ __launch_bounds__(1024, 1)
void lstm_kernel(const float* __restrict__ conds, const float* __restrict__ W1,
                 const float* __restrict__ b1, const float* __restrict__ W2,
                 const float* __restrict__ b2, const float* __restrict__ bo,
                 const int* __restrict__ seqp,
                 const ushort* __restrict__ wfrag, const ushort* __restrict__ wofrag,
                 const float* __restrict__ bsum, const float* __restrict__ bsum_t0,
                 float* __restrict__ out) {
  // 5 h-buffers (9216 B) + gate-buf (16384) + wo (2048) = 64512 B
  __shared__ __align__(16) char smem[64512];
  float* fc = (float*)smem;  // prologue alias over h-buffers 0..1
#define HBUF(i) ((ushort*)(smem + (i) * 9216))

  const int tid = threadIdx.x;
  const int w = tid >> 6;
  const int lane = tid & 63;
  const int c16 = lane & 15;
  const int q = lane >> 4;
  const int role = (w >> 2) & 1;                // 0: [i|f]  1: [g|o]
  const int ws = (w & 3) | ((w >> 3) << 2);     // hcol slice
  const int hi16 = (c16 < 8) ? 0 : 16;
  const int colw = ws * 8 + (c16 & 7);
  const int sA = (c16 >> 2) & 3;
  const int qs8 = (q ^ sA) * 8;                 // swizzled A-read col offset
  const int wcol = (colw & 7) + 8 * (ws ^ q);   // swizzled h-write col
  const int prbase = role * 32;                 // act row-half
  const int T = *seqp;
  const int row0 = blockIdx.x * 64;

  // gate-exchange pointers (fp16; write own other-half mtiles, read partner's)
  char* gw0 = smem + GB_OFF + (ws * 4 + (role ? 0 : 2)) * 512 + (c16 * 4 + q) * 8;
  char* gr_lo = smem + GB_OFF + (ws * 4 + (role ? 2 : 0) + ((c16 < 8) ? 0 : 1)) * 512 +
                ((c16 & 7) * 4 + q) * 8;

  // ---- prologue A: h1 = relu(conds @ W1^T + b1) -> fc ----
  {
    const int r = tid >> 4;
    const int i4 = (tid & 15) * 4;
    float xr[8];
#pragma unroll
    for (int k = 0; k < 8; ++k) xr[k] = conds[(long)(row0 + r) * 8 + k];
#pragma unroll
    for (int jj = 0; jj < 4; ++jj) {
      float s = b1[i4 + jj];
#pragma unroll
      for (int k = 0; k < 8; ++k) s = fmaf(xr[k], W1[(i4 + jj) * 8 + k], s);
      fc[r * 64 + i4 + jj] = fmaxf(s, 0.0f);
    }
  }
  __syncthreads();

  // ---- prologue B1: per-lane fp32 c0 for this wave's row-half ----
  float cinit[4];
  {
    const float b2v = b2[64 + colw];
#pragma unroll
    for (int r = 0; r < 4; ++r) cinit[r] = b2v;
    const float* w2r = W2 + (64 + colw) * 64;
    const int rbase = prbase + hi16 + q * 4;
    for (int k4 = 0; k4 < 16; ++k4) {
      float4g wv = *(const float4g*)(w2r + k4 * 4);
#pragma unroll
      for (int r = 0; r < 4; ++r) {
        float4g hv = *(const float4g*)(fc + (rbase + r) * 64 + k4 * 4);
        cinit[r] = fmaf(hv.x, wv.x, cinit[r]);
        cinit[r] = fmaf(hv.y, wv.y, cinit[r]);
        cinit[r] = fmaf(hv.z, wv.z, cinit[r]);
        cinit[r] = fmaf(hv.w, wv.w, cinit[r]);
      }
    }
  }
  // ---- prologue B2: h0 (4 cols per thread) ----
  float ce0[4];
  {
    const int rb = tid >> 4;
    const int cb = (tid & 15) * 4;
#pragma unroll
    for (int jj = 0; jj < 4; ++jj) {
      float s = b2[cb + jj];
      for (int k = 0; k < 64; k += 4) {
        float4g hv = *(const float4g*)(fc + rb * 64 + k);
        float4g wv = *(const float4g*)(W2 + (cb + jj) * 64 + k);
        s = fmaf(hv.x, wv.x, s); s = fmaf(hv.y, wv.y, s);
        s = fmaf(hv.z, wv.z, s); s = fmaf(hv.w, wv.w, s);
      }
      ce0[jj] = s;
    }
  }
  // ---- weight fragments (64 regs) ----
  short8 wreg[4][4];
  {
    const ushort* base = wfrag + w * 8192;
#pragma unroll
    for (int l = 0; l < 4; ++l)
#pragma unroll
      for (int kc = 0; kc < 4; ++kc)
        wreg[l][kc] = *(const short8*)(base + ((l * 4 + kc) * 64 + lane) * 8);
  }
  if (tid < 512) ((unsigned*)(smem + WO_OFF))[tid] = ((const unsigned*)wofrag)[tid];
  // ---- raw biases (folded into acc init) ----
  const int gate = role * 2 + ((c16 >= 8) ? 1 : 0);
  float blane[4];
#pragma unroll
  for (int l = 0; l < 4; ++l) blane[l] = bsum[l * 256 + gate * 64 + colw];
  const float bl00 = bsum_t0[gate * 64 + colw];
  const float boc = (c16 < 3) ? bo[c16] : 0.0f;
  __syncthreads();

  // ---- prologue C: scatter h0 into buffers 0..3 (swizzled, b64 stores) ----
  {
    const int rb = tid >> 4;
    const int cb = (tid & 15) * 4;
    const int scol = (((cb >> 3) ^ ((rb >> 2) & 3)) * 8) + (cb & 7);
    short4v hv;
#pragma unroll
    for (int jj = 0; jj < 4; ++jj) hv[jj] = (short)f2bf_fast(ce0[jj]);
#pragma unroll
    for (int b = 0; b < 4; ++b) *(short4v*)(HBUF(b) + rb * 72 + scol) = hv;
  }
  // c-state (one row-half, 4 layers)
  float cr[4][4];
#pragma unroll
  for (int l = 0; l < 4; ++l)
#pragma unroll
    for (int r = 0; r < 4; ++r) cr[l][r] = cinit[r];
  __syncthreads();

  // ---- warm-up: rec MFMAs + bias init for (t=0, l=0) ----
  f32x4 acc0, acc1, acc2, acc3;
  {
    const ushort* hcN = HBUF(0);
    RECB(acc0, 0, hcN, bl00, 0) RECB(acc1, 1, hcN, bl00, 0)
    RECB(acc2, 2, hcN, bl00, 0) RECB(acc3, 3, hcN, bl00, 0)
  }
  int cur[4] = {0, 1, 2, 3};
  int spare = 4;

  for (int t = 0; t < T; ++t) {
#pragma unroll
    for (int l = 0; l < 4; ++l) {
      // ---- W1: input-half MFMAs + exchange-write (+pred) ----
      const ushort* hp = HBUF((l == 0) ? cur[3] : cur[l - 1]);
      if (t + l != 0) {  // (0,0): x0 contribution folded into bl00 -> skip
        INB(acc0, 0, hp, l) INB(acc1, 1, hp, l) INB(acc2, 2, hp, l) INB(acc3, 3, hp, l)
      }
      if (!role) {  // IF exports mt2,3 (i|f) for GO's act rows
        *(uint2v*)gw0 = (uint2v){pk16(acc2[0], acc2[1]), pk16(acc2[2], acc2[3])};
        *(uint2v*)(gw0 + 512) = (uint2v){pk16(acc3[0], acc3[1]), pk16(acc3[2], acc3[3])};
      } else {      // GO exports mt0,1 (g|o)
        *(uint2v*)gw0 = (uint2v){pk16(acc0[0], acc0[1]), pk16(acc0[2], acc0[3])};
        *(uint2v*)(gw0 + 512) = (uint2v){pk16(acc1[0], acc1[1]), pk16(acc1[2], acc1[3])};
      }
      if (l == 0 && t > 0 && w < 4) {  // pred out[t-1] from h3(t-1), store-only
        const ushort* h3 = HBUF(cur[3]);
        const int arow = w * 16 + c16;
        short8 p0 = *(const short8*)(h3 + arow * 72 + qs8);
        short8 p1 = *(const short8*)(h3 + arow * 72 + 32 + qs8);
        short8 wo0v = *(const short8*)((ushort*)(smem + WO_OFF) + lane * 8);
        short8 wo1v = *(const short8*)((ushort*)(smem + WO_OFF) + 512 + lane * 8);
        f32x4 P = {0.f, 0.f, 0.f, 0.f};
        P = __builtin_amdgcn_mfma_f32_16x16x32_bf16(p0, wo0v, P, 0, 0, 0);
        P = __builtin_amdgcn_mfma_f32_16x16x32_bf16(p1, wo1v, P, 0, 0, 0);
        if (c16 < 3) {
#pragma unroll
          for (int r = 0; r < 4; ++r) {
            int rloc = w * 16 + q * 4 + r;
            out[(long)(row0 + rloc) * (3 * T) + (long)(t - 1) * 3 + c16] = P[r] + boc;
          }
        }
      }
      barrier_lgkm();
      // ---- W2: gate exchange read, extract own gates, rec(next), act, h-write ----
      half4 hA = *(const half4*)gr_lo;          // partner lo-half gate (g for IF, i for GO)
      half4 hB = *(const half4*)(gr_lo + 256);  // partner hi-half gate (o for IF, f for GO)
      float ownA[4], ownB[4];
      if (!role) {
#pragma unroll
        for (int r = 0; r < 4; ++r) {
          ownA[r] = pkmerge<0xC>(acc0[r], acc1[r]);  // i
          ownB[r] = pkmerge<0x3>(acc1[r], acc0[r]);  // f
        }
      } else {
#pragma unroll
        for (int r = 0; r < 4; ++r) {
          ownA[r] = pkmerge<0xC>(acc2[r], acc3[r]);  // g
          ownB[r] = pkmerge<0x3>(acc3[r], acc2[r]);  // o
        }
      }
      const int sp = spare; spare = cur[l]; cur[l] = sp;  // rotate h buffer
      ushort* wbuf = HBUF(sp);
      // rec MFMAs + bias init for next step (acc now dead)
      {
        const int ln = (l + 1) & 3;
        const ushort* hcN = HBUF(cur[ln]);
        const float bN = blane[ln];
        RECB(acc0, 0, hcN, bN, ln) RECB(acc1, 1, hcN, bN, ln)
        RECB(acc2, 2, hcN, bN, ln) RECB(acc3, 3, hcN, bN, ln)
      }
      // act (4 elements, this wave's row-half)
      ushort* wb = wbuf + (prbase + hi16 + q * 4) * 72 + wcol;
#pragma unroll
      for (int r = 0; r < 4; ++r) {
        float pA = (float)hA[r], pB = (float)hB[r];
        float gi = role ? pA : ownA[r];
        float gf = role ? pB : ownB[r];
        float gg = role ? ownA[r] : pA;
        float go = role ? ownB[r] : pB;
        float Ei = __builtin_amdgcn_exp2f(gi * -LOG2E);
        float Ef = __builtin_amdgcn_exp2f(gf * -LOG2E);
        float Eg = __builtin_amdgcn_exp2f(gg * (-2.0f * LOG2E));
        float Eo = __builtin_amdgcn_exp2f(go * -LOG2E);
        float Di = 1.0f + Ei, Df = 1.0f + Ef, Dg = 1.0f + Eg, Do = 1.0f + Eo;
        float P = Di * Dg;
        float t3 = fmaf(-Eg, Df, Df);              // Df*(1-Eg)
        float num = fmaf(cr[l][r], P, t3);         // c*Di*Dg + Df*(1-Eg)
        float R = __builtin_amdgcn_rcpf(Df * P);
        float cn = num * R;
        cr[l][r] = cn;
        float Ec = __builtin_amdgcn_exp2f(cn * (-2.0f * LOG2E));
        float Dc = 1.0f + Ec;
        float R2 = __builtin_amdgcn_rcpf(Do * Dc);
        wb[r * 72] = f2bf_fast((1.0f - Ec) * R2);  // sig(o)*tanh(cn)
      }
      barrier_lgkm();
    }
  }
  // ---- final pred: out[T-1] from h3(T-1) ----
  if (w < 4) {
    const ushort* h3 = HBUF(cur[3]);
    const int arow = w * 16 + c16;
    short8 p0 = *(const short8*)(h3 + arow * 72 + qs8);
    short8 p1 = *(const short8*)(h3 + arow * 72 + 32 + qs8);
    short8 wo0v = *(const short8*)((ushort*)(smem + WO_OFF) + lane * 8);
    short8 wo1v = *(const short8*)((ushort*)(smem + WO_OFF) + 512 + lane * 8);
    f32x4 P = {0.f, 0.f, 0.f, 0.f};
    P = __builtin_amdgcn_mfma_f32_16x16x32_bf16(p0, wo0v, P, 0, 0, 0);
    P = __builtin_amdgcn_mfma_f32_16x16x32_bf16(p1, wo1v, P, 0, 0, 0);
    if (c16 < 3) {
#pragma unroll
      for (int r = 0; r < 4; ++r) {
        int rloc = w * 16 + q * 4 + r;
        out[(long)(row0 + rloc) * (3 * T) + (long)(T - 1) * 3 + c16] = P[r] + boc;
      }
    }
  }
}

extern "C" void kernel_launch(void* const* d_in, const int* in_sizes, int n_in,
                              void* d_out, int out_size, void* d_ws, size_t ws_size,
                              hipStream_t stream) {
  const float* conds = (const float*)d_in[0];
  const float* W1    = (const float*)d_in[1];
  const float* b1    = (const float*)d_in[2];
  const float* W2    = (const float*)d_in[3];
  const float* b2    = (const float*)d_in[4];
  const float* Wih0  = (const float*)d_in[5];
  const float* Wihr  = (const float*)d_in[6];
  const float* Whh   = (const float*)d_in[7];
  const float* bih   = (const float*)d_in[8];
  const float* bhh   = (const float*)d_in[9];
  const float* Wo    = (const float*)d_in[10];
  const float* bo    = (const float*)d_in[11];
  const int*   seqp  = (const int*)d_in[12];

  const int B = in_sizes[0] / 8;  // 65536

  ushort* wfrag = (ushort*)d_ws;             // 131072 shorts
  ushort* wofrag = wfrag + 131072;           // 1024 shorts
  float* bsum = (float*)(wofrag + 1024);     // 1024 floats
  float* bsum_t0 = bsum + 1024;              // 256 floats

  prep_kernel<<<521, 256, 0, stream>>>(Wih0, Wihr, Whh, bih, bhh, Wo, bo,
                                       wfrag, wofrag, bsum, bsum_t0);
  lstm_kernel<<<B / 64, 1024, 0, stream>>>(conds, W1, b1, W2, b2, bo, seqp,
                                           wfrag, wofrag, bsum, bsum_t0, (float*)d_out);
}

// Round 8
// 3630.333 us; speedup vs baseline: 1.0724x; 1.0724x over previous
//
#include <hip/hip_runtime.h>
#include <hip/hip_bf16.h>

typedef short short8 __attribute__((ext_vector_type(8)));
typedef short short4v __attribute__((ext_vector_type(4)));
typedef float f32x4 __attribute__((ext_vector_type(4)));
typedef float float4g __attribute__((ext_vector_type(4)));
typedef unsigned int uint2v __attribute__((ext_vector_type(2)));
typedef __fp16 half4 __attribute__((ext_vector_type(4)));
typedef unsigned short ushort;

#define LOG2E 1.44269504088896f
#define GB_OFF 46080   // gate-exchange buffer (16384 B)
#define WO_OFF 62464   // Wo fragments (2048 B)

__device__ __forceinline__ ushort f2bf_fast(float f) {
  unsigned u = __builtin_bit_cast(unsigned, f);
  return (ushort)((u + 0x8000u) >> 16);
}
template <int BM>
__device__ __forceinline__ float pkmerge(float oldv, float srcv) {
  int o = __builtin_bit_cast(int, oldv);
  int s = __builtin_bit_cast(int, srcv);
  int r = __builtin_amdgcn_update_dpp(o, s, 0x128 /*row_ror:8*/, 0xF, BM, false);
  return __builtin_bit_cast(float, r);
}
__device__ __forceinline__ void barrier_lgkm() {
  asm volatile("s_waitcnt lgkmcnt(0)\n\ts_barrier" ::: "memory");
}
__device__ __forceinline__ unsigned pk16(float a, float b) {
  auto r = __builtin_amdgcn_cvt_pkrtz(a, b);  // __fp16 ext_vector(2)
  return __builtin_bit_cast(unsigned, r);
}

// ---------------- prep: weights -> bf16 MFMA B-frag blocks, 16 wave-slots ----------------
// wfrag: [wslot(16)][l(4)][kc(4)][lane(64)][8 bf16]; wslot: role=(w>>2)&1 (0:[i|f] 1:[g|o]),
// ws=(w&3)|((w>>3)<<2) -> hcols ws*8..+8. l=0 K<64 holds Wx=Wih0@Wo (pred folded), bias +Wih0@bo;
// t0 bias set: b + Wih0@x0.
__global__ void prep_kernel(const float* __restrict__ Wih0, const float* __restrict__ Wihr,
                            const float* __restrict__ Whh, const float* __restrict__ bih,
                            const float* __restrict__ bhh, const float* __restrict__ Wo,
                            const float* __restrict__ bo,
                            ushort* __restrict__ wfrag, ushort* __restrict__ wofrag,
                            float* __restrict__ bsum, float* __restrict__ bsum_t0) {
  int id = blockIdx.x * 256 + threadIdx.x;
  if (id < 131072) {
    int j = id & 7, lane = (id >> 3) & 63, kc = (id >> 9) & 3, l = (id >> 11) & 3,
        wslot = id >> 13;
    int role = (wslot >> 2) & 1, ws = (wslot & 3) | ((wslot >> 3) << 2);
    int c16 = lane & 15, qq = lane >> 4;
    int gate = role * 2 + (c16 >= 8 ? 1 : 0);
    int n = gate * 64 + ws * 8 + (c16 & 7);
    int k = kc * 32 + qq * 8 + j;
    float v;
    if (k < 64) {
      if (l == 0)
        v = Wih0[n * 3 + 0] * Wo[k] + Wih0[n * 3 + 1] * Wo[64 + k] +
            Wih0[n * 3 + 2] * Wo[128 + k];
      else
        v = Wihr[((l - 1) * 256 + n) * 64 + k];
    } else {
      v = Whh[(l * 256 + n) * 64 + (k - 64)];
    }
    wfrag[id] = f2bf_fast(v);
  } else if (id < 132096) {
    int id2 = id - 131072;
    int j = id2 & 7, lane = (id2 >> 3) & 63, kc = id2 >> 9;
    int c16 = lane & 15, qq = lane >> 4;
    int k = kc * 32 + qq * 8 + j;
    float v = (c16 < 3) ? Wo[c16 * 64 + k] : 0.0f;
    wofrag[id2] = f2bf_fast(v);
  } else if (id < 133120) {
    int n2 = id - 132096;
    float v = bih[n2] + bhh[n2];
    if (n2 < 256)
      v += Wih0[n2 * 3 + 0] * bo[0] + Wih0[n2 * 3 + 1] * bo[1] + Wih0[n2 * 3 + 2] * bo[2];
    bsum[n2] = v;
  } else if (id < 133376) {
    int n = id - 133120;
    bsum_t0[n] = bih[n] + bhh[n] + 0.5f * (Wih0[n * 3 + 0] + Wih0[n * 3 + 1]);
  }
}

// rec-half MFMAs, acc init = bias splat (bias rides through MFMA C)
#define RECB(accv, mt, hcN, bN, LN)                                                   \
  {                                                                                   \
    const int arow = (mt) * 16 + c16;                                                 \
    short8 a2 = *(const short8*)((hcN) + arow * 72 + qs8);                            \
    short8 a3 = *(const short8*)((hcN) + arow * 72 + 32 + qs8);                       \
    f32x4 A = {bN, bN, bN, bN};                                                       \
    A = __builtin_amdgcn_mfma_f32_16x16x32_bf16(a2, wreg[LN][2], A, 0, 0, 0);         \
    A = __builtin_amdgcn_mfma_f32_16x16x32_bf16(a3, wreg[LN][3], A, 0, 0, 0);         \
    accv = A;                                                                         \
  }
// input-half MFMAs (accumulate)
#define INB(accv, mt, hpp, LN)                                                        \
  {                                                                                   \
    const int arow = (mt) * 16 + c16;                                                 \
    short8 a0 = *(const short8*)((hpp) + arow * 72 + qs8);                            \
    short8 a1 = *(const short8*)((hpp) + arow * 72 + 32 + qs8);                       \
    accv = __builtin_amdgcn_mfma_f32_16x16x32_bf16(a0, wreg[LN][0], accv, 0, 0, 0);   \
    accv = __builtin_amdgcn_mfma_f32_16x16x32_bf16(a1, wreg[LN][1], accv, 0, 0, 0);   \
  }
// one act element: gi,gf,gg,go -> update c, write h (shared-denominator, 5 exp + 2 rcp)
#define ACT_ONE(gi, gf, gg, go, cref, wbp)                                            \
  {                                                                                   \
    float Ei = __builtin_amdgcn_exp2f((gi) * -LOG2E);                                 \
    float Ef = __builtin_amdgcn_exp2f((gf) * -LOG2E);                                 \
    float Eg = __builtin_amdgcn_exp2f((gg) * (-2.0f * LOG2E));                        \
    float Eo = __builtin_amdgcn_exp2f((go) * -LOG2E);                                 \
    float Di = 1.0f + Ei, Df = 1.0f + Ef, Dg = 1.0f + Eg, Do = 1.0f + Eo;             \
    float Pd = Di * Dg;                                                               \
    float t3 = fmaf(-Eg, Df, Df);                                                     \
    float num = fmaf(cref, Pd, t3);                                                   \
    float Rr = __builtin_amdgcn_rcpf(Df * Pd);                                        \
    float cn = num * Rr;                                                              \
    cref = cn;                                                                        \
    float Ec = __builtin_amdgcn_exp2f(cn * (-2.0f * LOG2E));                          \
    float Dc = 1.0f + Ec;                                                             \
    float R2 = __builtin_amdgcn_rcpf(Do * Dc);                                        \
    *(wbp) = f2bf_fast((1.0f - Ec) * R2);                                             \
  }

// ---------------- main persistent LSTM kernel ----------------
// 16 waves (1024 thr), 64 rows/block, 4 waves/SIMD (128-reg combined budget).
// Wave = 1 gate-pair tile x 4 layers: 64 weight regs PINNED to AGPR via asm (+16 acc
// AGPR = 80). Arch side kept <=48: lazy gate extraction (act r0,1 straight from acc),
// pred in W2 where acc slots are dead. 2 lgkm-only barriers per layer-step.
__global__ __launch_bounds__(1024, 4)
void lstm_kernel(const float* __restrict__ conds, const float* __restrict__ W1,
                 const float* __restrict__ b1, const float* __restrict__ W2,
                 const float* __restrict__ b2, const float* __restrict__ bo,
                 const int* __restrict__ seqp,
                 const ushort* __restrict__ wfrag, const ushort* __restrict__ wofrag,
                 const float* __restrict__ bsum, const float* __restrict__ bsum_t0,
                 float* __restrict__ out) {
  // 5 h-buffers (9216 B) + gate-buf (16384) + wo (2048) = 64512 B
  __shared__ __align__(16) char smem[64512];
  float* fc = (float*)smem;  // prologue alias over h-buffers 0..1
#define HBUF(i) ((ushort*)(smem + (i) * 9216))

  const int tid = threadIdx.x;
  const int w = tid >> 6;
  const int lane = tid & 63;
  const int c16 = lane & 15;
  const int q = lane >> 4;
  const int role = (w >> 2) & 1;                // 0: [i|f]  1: [g|o]
  const int ws = (w & 3) | ((w >> 3) << 2);     // hcol slice
  const int hi16 = (c16 < 8) ? 0 : 16;
  const int colw = ws * 8 + (c16 & 7);
  const int sA = (c16 >> 2) & 3;
  const int qs8 = (q ^ sA) * 8;                 // swizzled A-read col offset
  const int wcol = (colw & 7) + 8 * (ws ^ q);   // swizzled h-write col
  const int prbase = role * 32;                 // act row-half
  const int T = *seqp;
  const int row0 = blockIdx.x * 64;

  // gate-exchange pointers (fp16; write own other-half mtiles, read partner's)
  char* gw0 = smem + GB_OFF + (ws * 4 + (role ? 0 : 2)) * 512 + (c16 * 4 + q) * 8;
  char* gr_lo = smem + GB_OFF + (ws * 4 + (role ? 2 : 0) + ((c16 < 8) ? 0 : 1)) * 512 +
                ((c16 & 7) * 4 + q) * 8;

  // ---- prologue A: h1 = relu(conds @ W1^T + b1) -> fc ----
  {
    const int r = tid >> 4;
    const int i4 = (tid & 15) * 4;
    float xr[8];
#pragma unroll
    for (int k = 0; k < 8; ++k) xr[k] = conds[(long)(row0 + r) * 8 + k];
#pragma unroll
    for (int jj = 0; jj < 4; ++jj) {
      float s = b1[i4 + jj];
#pragma unroll
      for (int k = 0; k < 8; ++k) s = fmaf(xr[k], W1[(i4 + jj) * 8 + k], s);
      fc[r * 64 + i4 + jj] = fmaxf(s, 0.0f);
    }
  }
  __syncthreads();

  // ---- prologue B1: per-lane fp32 c0 for this wave's row-half ----
  float cinit[4];
  {
    const float b2v = b2[64 + colw];
#pragma unroll
    for (int r = 0; r < 4; ++r) cinit[r] = b2v;
    const float* w2r = W2 + (64 + colw) * 64;
    const int rbase = prbase + hi16 + q * 4;
    for (int k4 = 0; k4 < 16; ++k4) {
      float4g wv = *(const float4g*)(w2r + k4 * 4);
#pragma unroll
      for (int r = 0; r < 4; ++r) {
        float4g hv = *(const float4g*)(fc + (rbase + r) * 64 + k4 * 4);
        cinit[r] = fmaf(hv.x, wv.x, cinit[r]);
        cinit[r] = fmaf(hv.y, wv.y, cinit[r]);
        cinit[r] = fmaf(hv.z, wv.z, cinit[r]);
        cinit[r] = fmaf(hv.w, wv.w, cinit[r]);
      }
    }
  }
  // ---- prologue B2: h0 (4 cols per thread) ----
  float ce0[4];
  {
    const int rb = tid >> 4;
    const int cb = (tid & 15) * 4;
#pragma unroll
    for (int jj = 0; jj < 4; ++jj) {
      float s = b2[cb + jj];
      for (int k = 0; k < 64; k += 4) {
        float4g hv = *(const float4g*)(fc + rb * 64 + k);
        float4g wv = *(const float4g*)(W2 + (cb + jj) * 64 + k);
        s = fmaf(hv.x, wv.x, s); s = fmaf(hv.y, wv.y, s);
        s = fmaf(hv.z, wv.z, s); s = fmaf(hv.w, wv.w, s);
      }
      ce0[jj] = s;
    }
  }
  // ---- weight fragments: load and PIN to AGPR (64 regs, remat-proof) ----
  short8 wreg[4][4];
  {
    const ushort* base = wfrag + w * 8192;
#pragma unroll
    for (int l = 0; l < 4; ++l)
#pragma unroll
      for (int kc = 0; kc < 4; ++kc) {
        wreg[l][kc] = *(const short8*)(base + ((l * 4 + kc) * 64 + lane) * 8);
        asm volatile("" : "+a"(wreg[l][kc]));
      }
  }
  if (tid < 512) ((unsigned*)(smem + WO_OFF))[tid] = ((const unsigned*)wofrag)[tid];
  // ---- raw biases (folded into acc init) ----
  const int gate = role * 2 + ((c16 >= 8) ? 1 : 0);
  float blane[4];
#pragma unroll
  for (int l = 0; l < 4; ++l) blane[l] = bsum[l * 256 + gate * 64 + colw];
  const float bl00 = bsum_t0[gate * 64 + colw];
  const float boc = (c16 < 3) ? bo[c16] : 0.0f;
  __syncthreads();

  // ---- prologue C: scatter h0 into buffers 0..3 (swizzled, b64 stores) ----
  {
    const int rb = tid >> 4;
    const int cb = (tid & 15) * 4;
    const int scol = (((cb >> 3) ^ ((rb >> 2) & 3)) * 8) + (cb & 7);
    short4v hv;
#pragma unroll
    for (int jj = 0; jj < 4; ++jj) hv[jj] = (short)f2bf_fast(ce0[jj]);
#pragma unroll
    for (int b = 0; b < 4; ++b) *(short4v*)(HBUF(b) + rb * 72 + scol) = hv;
  }
  // c-state (one row-half, 4 layers)
  float cr[4][4];
#pragma unroll
  for (int l = 0; l < 4; ++l)
#pragma unroll
    for (int r = 0; r < 4; ++r) cr[l][r] = cinit[r];
  __syncthreads();

  // ---- warm-up: rec MFMAs + bias init for (t=0, l=0) ----
  f32x4 acc0, acc1, acc2, acc3;
  {
    const ushort* hcN = HBUF(0);
    RECB(acc0, 0, hcN, bl00, 0) RECB(acc1, 1, hcN, bl00, 0)
    RECB(acc2, 2, hcN, bl00, 0) RECB(acc3, 3, hcN, bl00, 0)
  }
  int cur[4] = {0, 1, 2, 3};
  int spare = 4;

  for (int t = 0; t < T; ++t) {
#pragma unroll
    for (int l = 0; l < 4; ++l) {
      // ---- W1: input-half MFMAs + exchange-write ----
      const ushort* hp = HBUF((l == 0) ? cur[3] : cur[l - 1]);
      if (t + l != 0) {  // (0,0): x0 contribution folded into bl00 -> skip
        INB(acc0, 0, hp, l) INB(acc1, 1, hp, l) INB(acc2, 2, hp, l) INB(acc3, 3, hp, l)
      }
      if (!role) {  // IF exports mt2,3 (i|f) for GO's act rows
        *(uint2v*)gw0 = (uint2v){pk16(acc2[0], acc2[1]), pk16(acc2[2], acc2[3])};
        *(uint2v*)(gw0 + 512) = (uint2v){pk16(acc3[0], acc3[1]), pk16(acc3[2], acc3[3])};
      } else {      // GO exports mt0,1 (g|o)
        *(uint2v*)gw0 = (uint2v){pk16(acc0[0], acc0[1]), pk16(acc0[2], acc0[3])};
        *(uint2v*)(gw0 + 512) = (uint2v){pk16(acc1[0], acc1[1]), pk16(acc1[2], acc1[3])};
      }
      barrier_lgkm();
      // ---- W2 ----
      half4 hA = *(const half4*)gr_lo;          // partner lo-half gate
      half4 hB = *(const half4*)(gr_lo + 256);  // partner hi-half gate
      const int sp = spare; spare = cur[l]; cur[l] = sp;  // rotate h buffer
      ushort* wb = HBUF(sp) + (prbase + hi16 + q * 4) * 72 + wcol;
      // act r=0,1: own gates straight from acc (before RECB overwrites)
#pragma unroll
      for (int r = 0; r < 2; ++r) {
        float oA, oB;
        if (!role) { oA = pkmerge<0xC>(acc0[r], acc1[r]); oB = pkmerge<0x3>(acc1[r], acc0[r]); }
        else       { oA = pkmerge<0xC>(acc2[r], acc3[r]); oB = pkmerge<0x3>(acc3[r], acc2[r]); }
        float pA = (float)hA[r], pB = (float)hB[r];
        float gi = role ? pA : oA, gf = role ? pB : oB;
        float gg = role ? oA : pA, go = role ? oB : pB;
        ACT_ONE(gi, gf, gg, go, cr[l][r], wb + r * 72)
      }
      // extract own gates for r=2,3 (4 regs), acc then dead
      float o2A[2], o2B[2];
#pragma unroll
      for (int r = 2; r < 4; ++r) {
        if (!role) { o2A[r - 2] = pkmerge<0xC>(acc0[r], acc1[r]); o2B[r - 2] = pkmerge<0x3>(acc1[r], acc0[r]); }
        else       { o2A[r - 2] = pkmerge<0xC>(acc2[r], acc3[r]); o2B[r - 2] = pkmerge<0x3>(acc3[r], acc2[r]); }
      }
      // pred (l==0, t>0): out[t-1] from h3(t-1); P reuses freed acc AGPRs
      if (l == 0 && t > 0 && w < 4) {
        const ushort* h3 = HBUF(cur[3]);
        const int arow = w * 16 + c16;
        short8 p0 = *(const short8*)(h3 + arow * 72 + qs8);
        short8 p1 = *(const short8*)(h3 + arow * 72 + 32 + qs8);
        short8 wo0v = *(const short8*)((ushort*)(smem + WO_OFF) + lane * 8);
        short8 wo1v = *(const short8*)((ushort*)(smem + WO_OFF) + 512 + lane * 8);
        f32x4 P = {0.f, 0.f, 0.f, 0.f};
        P = __builtin_amdgcn_mfma_f32_16x16x32_bf16(p0, wo0v, P, 0, 0, 0);
        P = __builtin_amdgcn_mfma_f32_16x16x32_bf16(p1, wo1v, P, 0, 0, 0);
        if (c16 < 3) {
#pragma unroll
          for (int r = 0; r < 4; ++r) {
            int rloc = w * 16 + q * 4 + r;
            out[(long)(row0 + rloc) * (3 * T) + (long)(t - 1) * 3 + c16] = P[r] + boc;
          }
        }
      }
      // rec MFMAs + bias init for next step
      {
        const int ln = (l + 1) & 3;
        const ushort* hcN = HBUF(cur[ln]);
        const float bN = blane[ln];
        RECB(acc0, 0, hcN, bN, ln) RECB(acc1, 1, hcN, bN, ln)
        RECB(acc2, 2, hcN, bN, ln) RECB(acc3, 3, hcN, bN, ln)
      }
      // act r=2,3 (overlaps rec MFMAs)
#pragma unroll
      for (int r = 2; r < 4; ++r) {
        float pA = (float)hA[r], pB = (float)hB[r];
        float oA = o2A[r - 2], oB = o2B[r - 2];
        float gi = role ? pA : oA, gf = role ? pB : oB;
        float gg = role ? oA : pA, go = role ? oB : pB;
        ACT_ONE(gi, gf, gg, go, cr[l][r], wb + r * 72)
      }
      barrier_lgkm();
    }
  }
  // ---- final pred: out[T-1] from h3(T-1) ----
  if (w < 4) {
    const ushort* h3 = HBUF(cur[3]);
    const int arow = w * 16 + c16;
    short8 p0 = *(const short8*)(h3 + arow * 72 + qs8);
    short8 p1 = *(const short8*)(h3 + arow * 72 + 32 + qs8);
    short8 wo0v = *(const short8*)((ushort*)(smem + WO_OFF) + lane * 8);
    short8 wo1v = *(const short8*)((ushort*)(smem + WO_OFF) + 512 + lane * 8);
    f32x4 P = {0.f, 0.f, 0.f, 0.f};
    P = __builtin_amdgcn_mfma_f32_16x16x32_bf16(p0, wo0v, P, 0, 0, 0);
    P = __builtin_amdgcn_mfma_f32_16x16x32_bf16(p1, wo1v, P, 0, 0, 0);
    if (c16 < 3) {
#pragma unroll
      for (int r = 0; r < 4; ++r) {
        int rloc = w * 16 + q * 4 + r;
        out[(long)(row0 + rloc) * (3 * T) + (long)(T - 1) * 3 + c16] = P[r] + boc;
      }
    }
  }
}

extern "C" void kernel_launch(void* const* d_in, const int* in_sizes, int n_in,
                              void* d_out, int out_size, void* d_ws, size_t ws_size,
                              hipStream_t stream) {
  const float* conds = (const float*)d_in[0];
  const float* W1    = (const float*)d_in[1];
  const float* b1    = (const float*)d_in[2];
  const float* W2    = (const float*)d_in[3];
  const float* b2    = (const float*)d_in[4];
  const float* Wih0  = (const float*)d_in[5];
  const float* Wihr  = (const float*)d_in[6];
  const float* Whh   = (const float*)d_in[7];
  const float* bih   = (const float*)d_in[8];
  const float* bhh   = (const float*)d_in[9];
  const float* Wo    = (const float*)d_in[10];
  const float* bo    = (const float*)d_in[11];
  const int*   seqp  = (const int*)d_in[12];

  const int B = in_sizes[0] / 8;  // 65536

  ushort* wfrag = (ushort*)d_ws;             // 131072 shorts
  ushort* wofrag = wfrag + 131072;           // 1024 shorts
  float* bsum = (float*)(wofrag + 1024);     // 1024 floats
  float* bsum_t0 = bsum + 1024;              // 256 floats

  prep_kernel<<<521, 256, 0, stream>>>(Wih0, Wihr, Whh, bih, bhh, Wo, bo,
                                       wfrag, wofrag, bsum, bsum_t0);
  lstm_kernel<<<B / 64, 1024, 0, stream>>>(conds, W1, b1, W2, b2, bo, seqp,
                                           wfrag, wofrag, bsum, bsum_t0, (float*)d_out);
}

// Round 9
// 1406.983 us; speedup vs baseline: 2.7669x; 2.5802x over previous
//
#include <hip/hip_runtime.h>
#include <hip/hip_bf16.h>

typedef short short8 __attribute__((ext_vector_type(8)));
typedef float f32x4 __attribute__((ext_vector_type(4)));
typedef float float4g __attribute__((ext_vector_type(4)));
typedef unsigned short ushort;

#define LOG2E 1.44269504088896f

__device__ __forceinline__ ushort f2bf_fast(float f) {
  unsigned u = __builtin_bit_cast(unsigned, f);
  return (ushort)((u + 0x8000u) >> 16);
}
template <int BM>
__device__ __forceinline__ float pkmerge(float oldv, float srcv) {
  int o = __builtin_bit_cast(int, oldv);
  int s = __builtin_bit_cast(int, srcv);
  int r = __builtin_amdgcn_update_dpp(o, s, 0x128 /*row_ror:8*/, 0xF, BM, false);
  return __builtin_bit_cast(float, r);
}
__device__ __forceinline__ void barrier_lgkm() {
  asm volatile("s_waitcnt lgkmcnt(0)\n\ts_barrier" ::: "memory");
}

// ---------------- prep: weights -> bf16 MFMA B-frag blocks (R4 8-wave layout) -------------
// wfrag: [w(8)][l(4)][nt(2)][kc(4)][lane(64)][8 bf16]; K = [in(64)|hidden(64)].
// Gate scales FOLDED into weights+biases: i,f,o rows x(-log2e); g rows x(-2log2e), so the
// MFMA output is directly the exp2 argument. l=0 K<64 holds Wx=Wih0@Wo (pred recursion
// folded); its bias gets +Wih0@bo. t0 bias set: b + Wih0@x0, x0=(0.5,0.5,0).
__global__ void prep_kernel(const float* __restrict__ Wih0, const float* __restrict__ Wihr,
                            const float* __restrict__ Whh, const float* __restrict__ bih,
                            const float* __restrict__ bhh, const float* __restrict__ Wo,
                            const float* __restrict__ bo,
                            ushort* __restrict__ wfrag, ushort* __restrict__ wofrag,
                            float* __restrict__ bsum, float* __restrict__ bsum_t0) {
  int id = blockIdx.x * 256 + threadIdx.x;
  if (id < 131072) {
    int j = id & 7, lane = (id >> 3) & 63, kc = (id >> 9) & 3, nt = (id >> 11) & 1,
        l = (id >> 12) & 3, w = id >> 14;
    int c16 = lane & 15, qq = lane >> 4;
    int gate = nt * 2 + (c16 >= 8 ? 1 : 0);
    int n = gate * 64 + w * 8 + (c16 & 7);
    int k = kc * 32 + qq * 8 + j;
    float v;
    if (k < 64) {
      if (l == 0)
        v = Wih0[n * 3 + 0] * Wo[k] + Wih0[n * 3 + 1] * Wo[64 + k] +
            Wih0[n * 3 + 2] * Wo[128 + k];
      else
        v = Wihr[((l - 1) * 256 + n) * 64 + k];
    } else {
      v = Whh[(l * 256 + n) * 64 + (k - 64)];
    }
    float sc = (gate == 2) ? (-2.0f * LOG2E) : (-LOG2E);
    wfrag[id] = f2bf_fast(v * sc);
  } else if (id < 132096) {
    int id2 = id - 131072;
    int j = id2 & 7, lane = (id2 >> 3) & 63, kc = id2 >> 9;
    int c16 = lane & 15, qq = lane >> 4;
    int k = kc * 32 + qq * 8 + j;
    float v = (c16 < 3) ? Wo[c16 * 64 + k] : 0.0f;   // pred weights: UNscaled
    wofrag[id2] = f2bf_fast(v);
  } else if (id < 133120) {
    int n2 = id - 132096;
    int gate = (n2 >> 6) & 3;
    float v = bih[n2] + bhh[n2];
    if (n2 < 256)  // layer 0: fold Wih0 @ bo
      v += Wih0[n2 * 3 + 0] * bo[0] + Wih0[n2 * 3 + 1] * bo[1] + Wih0[n2 * 3 + 2] * bo[2];
    bsum[n2] = v * ((gate == 2) ? (-2.0f * LOG2E) : (-LOG2E));
  } else if (id < 133376) {
    int n = id - 133120;
    int gate = (n >> 6) & 3;
    float v = bih[n] + bhh[n] + 0.5f * (Wih0[n * 3 + 0] + Wih0[n * 3 + 1]);
    bsum_t0[n] = v * ((gate == 2) ? (-2.0f * LOG2E) : (-LOG2E));
  }
}

// one act element (inputs are pre-scaled exp2 args): 5 exp2 + 2 rcp
#define ACT_ONE(gi, gf, gg, go, cref, wbp)                                            \
  {                                                                                   \
    float Ei = __builtin_amdgcn_exp2f(gi);                                            \
    float Ef = __builtin_amdgcn_exp2f(gf);                                            \
    float Eg = __builtin_amdgcn_exp2f(gg);                                            \
    float Eo = __builtin_amdgcn_exp2f(go);                                            \
    float Di = 1.0f + Ei, Df = 1.0f + Ef, Dg = 1.0f + Eg, Do = 1.0f + Eo;             \
    float Pd = Di * Dg;                                                               \
    float t3 = fmaf(-Eg, Df, Df);                                                     \
    float num = fmaf(cref, Pd, t3);                                                   \
    float Rr = __builtin_amdgcn_rcpf(Df * Pd);                                        \
    float cn = num * Rr;                                                              \
    cref = cn;                                                                        \
    float Ec = __builtin_amdgcn_exp2f(cn * (-2.0f * LOG2E));                          \
    float Dc = 1.0f + Ec;                                                             \
    float R2 = __builtin_amdgcn_rcpf(Do * Dc);                                        \
    *(wbp) = f2bf_fast((1.0f - Ec) * R2);                                             \
  }

// recurrent-half MFMAs for all 4 mtiles; acc init = pre-scaled bias splat
#define REC4(L, HC, BA, BB)                                                           \
  _Pragma("unroll")                                                                   \
  for (int mt = 0; mt < 4; ++mt) {                                                    \
    short8 a2 = *(const short8*)((HC) + (mt * 16 + c16) * 72 + qs8);                  \
    short8 a3 = *(const short8*)((HC) + (mt * 16 + c16) * 72 + 32 + qs8);             \
    f32x4 A = {BA, BA, BA, BA}, Bv = {BB, BB, BB, BB};                                \
    A  = __builtin_amdgcn_mfma_f32_16x16x32_bf16(a2, wreg[L][0][2], A, 0, 0, 0);      \
    A  = __builtin_amdgcn_mfma_f32_16x16x32_bf16(a3, wreg[L][0][3], A, 0, 0, 0);      \
    Bv = __builtin_amdgcn_mfma_f32_16x16x32_bf16(a2, wreg[L][1][2], Bv, 0, 0, 0);     \
    Bv = __builtin_amdgcn_mfma_f32_16x16x32_bf16(a3, wreg[L][1][3], Bv, 0, 0, 0);     \
    accA[mt] = A; accB[mt] = Bv;                                                      \
  }
// input-half MFMAs (accumulate)
#define IN4(L, HP)                                                                    \
  _Pragma("unroll")                                                                   \
  for (int mt = 0; mt < 4; ++mt) {                                                    \
    short8 a0 = *(const short8*)((HP) + (mt * 16 + c16) * 72 + qs8);                  \
    short8 a1 = *(const short8*)((HP) + (mt * 16 + c16) * 72 + 32 + qs8);             \
    accA[mt] = __builtin_amdgcn_mfma_f32_16x16x32_bf16(a0, wreg[L][0][0], accA[mt], 0, 0, 0); \
    accA[mt] = __builtin_amdgcn_mfma_f32_16x16x32_bf16(a1, wreg[L][0][1], accA[mt], 0, 0, 0); \
    accB[mt] = __builtin_amdgcn_mfma_f32_16x16x32_bf16(a0, wreg[L][1][0], accB[mt], 0, 0, 0); \
    accB[mt] = __builtin_amdgcn_mfma_f32_16x16x32_bf16(a1, wreg[L][1][1], accB[mt], 0, 0, 0); \
  }

// ---------------- main persistent LSTM kernel ----------------
// 8 waves (512 thr), 64 rows/block, 2 waves/SIMD. Weight-stationary: 128 wregs/wave.
// IN-PLACE h buffers (4 fixed, no rotation -> literal LDS addresses), ONE lgkm barrier
// per layer-step: segment = [barrier; IN(t,l); pred; act(t,l)->HBUF(l); REC(t,l+1)].
// Safety: REC reads h_l(t-1) in the segment BEFORE the barrier that precedes act's
// writes of h_l(t); all cross-wave read/write pairs are barrier-separated.
__global__ __launch_bounds__(512, 2)
void lstm_kernel(const float* __restrict__ conds, const float* __restrict__ W1,
                 const float* __restrict__ b1, const float* __restrict__ W2,
                 const float* __restrict__ b2, const float* __restrict__ bo,
                 const int* __restrict__ seqp,
                 const ushort* __restrict__ wfrag, const ushort* __restrict__ wofrag,
                 const float* __restrict__ bsum, const float* __restrict__ bsum_t0,
                 float* __restrict__ out) {
  // 4 h-buffers (64 rows x 72 ushort = 9216 B each) = 36864 B
  __shared__ __align__(16) char smem[4 * 9216];
  float* fc = (float*)smem;  // prologue alias over buffers 0..1 (16384 <= 18432)
#define HBUF(i) ((ushort*)(smem + (i) * 9216))

  const int tid = threadIdx.x;
  const int w = tid >> 6;
  const int lane = tid & 63;
  const int c16 = lane & 15;
  const int q = lane >> 4;
  const int hi16 = (c16 < 8) ? 0 : 16;   // packed-half row offset
  const int colw = w * 8 + (c16 & 7);    // this lane's h-column
  const int sA = (c16 >> 2) & 3;         // read swizzle (per-lane constant)
  const int qs8 = (q ^ sA) * 8;          // swizzled A-read col offset (ushorts)
  const int wcol = (colw & 7) + 8 * (w ^ q);  // swizzled write col
  const int T = *seqp;
  const int row0 = blockIdx.x * 64;

  // ---- prologue A: h1 = relu(conds @ W1^T + b1) -> fc ----
  {
    const int r = tid >> 3;
    const int i8 = (tid & 7) * 8;
    float xr[8];
#pragma unroll
    for (int k = 0; k < 8; ++k) xr[k] = conds[(long)(row0 + r) * 8 + k];
#pragma unroll
    for (int jj = 0; jj < 8; ++jj) {
      float s = b1[i8 + jj];
#pragma unroll
      for (int k = 0; k < 8; ++k) s = fmaf(xr[k], W1[(i8 + jj) * 8 + k], s);
      fc[r * 64 + i8 + jj] = fmaxf(s, 0.0f);
    }
  }
  __syncthreads();

  // ---- prologue B1: per-lane fp32 c0 at packed rows ----
  float cinit[2][4];
  {
    const float b2v = b2[64 + colw];
#pragma unroll
    for (int pr = 0; pr < 2; ++pr)
#pragma unroll
      for (int r = 0; r < 4; ++r) cinit[pr][r] = b2v;
    const float* w2r = W2 + (64 + colw) * 64;
    const int rbase = hi16 + q * 4;
#pragma unroll 2
    for (int k4 = 0; k4 < 16; ++k4) {
      float4g wv = *(const float4g*)(w2r + k4 * 4);
#pragma unroll
      for (int pr = 0; pr < 2; ++pr)
#pragma unroll
        for (int r = 0; r < 4; ++r) {
          float4g hv = *(const float4g*)(fc + (pr * 32 + rbase + r) * 64 + k4 * 4);
          cinit[pr][r] = fmaf(hv.x, wv.x, cinit[pr][r]);
          cinit[pr][r] = fmaf(hv.y, wv.y, cinit[pr][r]);
          cinit[pr][r] = fmaf(hv.z, wv.z, cinit[pr][r]);
          cinit[pr][r] = fmaf(hv.w, wv.w, cinit[pr][r]);
        }
    }
  }
  // ---- prologue B2: h0 cols (thread-per-row) ----
  float ce0[8];
  {
    const int rb = tid >> 3;
    const int cb = (tid & 7) * 8;
#pragma unroll
    for (int jj = 0; jj < 8; ++jj) {
      float s = b2[cb + jj];
      for (int k = 0; k < 64; k += 4) {
        float4g hv = *(const float4g*)(fc + rb * 64 + k);
        float4g wv = *(const float4g*)(W2 + (cb + jj) * 64 + k);
        s = fmaf(hv.x, wv.x, s); s = fmaf(hv.y, wv.y, s);
        s = fmaf(hv.z, wv.z, s); s = fmaf(hv.w, wv.w, s);
      }
      ce0[jj] = s;
    }
  }
  __syncthreads();

  // ---- prologue C: scatter h0 into buffers 0..3 (swizzled, b128 stores) ----
  {
    const int rb = tid >> 3;
    const int gsw = ((tid & 7) ^ ((rb >> 2) & 3)) * 8;
    short8 hv;
#pragma unroll
    for (int jj = 0; jj < 8; ++jj) hv[jj] = (short)f2bf_fast(ce0[jj]);
#pragma unroll
    for (int b = 0; b < 4; ++b)
      *(short8*)(HBUF(b) + rb * 72 + gsw) = hv;
  }

  // ---- weight fragments -> registers (128, land in AGPR as in R4) ----
  short8 wreg[4][2][4];
  {
    const ushort* base = wfrag + w * 16384;
#pragma unroll
    for (int l = 0; l < 4; ++l)
#pragma unroll
      for (int nt = 0; nt < 2; ++nt)
#pragma unroll
        for (int kc = 0; kc < 4; ++kc)
          wreg[l][nt][kc] = *(const short8*)(base + (((l * 2 + nt) * 4 + kc) * 64 + lane) * 8);
  }
  short8 wo0 = *(const short8*)(wofrag + lane * 8);
  short8 wo1 = *(const short8*)(wofrag + 512 + lane * 8);

  // pre-scaled biases for acc init (per lane: nt0 tile -> i|f, nt1 tile -> g|o)
  const int g0 = (c16 >= 8) ? 64 : 0;
  float bA[4], bB[4];
#pragma unroll
  for (int l = 0; l < 4; ++l) {
    bA[l] = bsum[l * 256 + g0 + colw];
    bB[l] = bsum[l * 256 + 128 + g0 + colw];
  }
  const float bA0 = bsum_t0[g0 + colw];
  const float bB0 = bsum_t0[128 + g0 + colw];
  const float boc = (c16 < 3) ? bo[c16] : 0.0f;

  // c-state fp32, packed layout
  float cr[4][2][4];
#pragma unroll
  for (int l = 0; l < 4; ++l)
#pragma unroll
    for (int pr = 0; pr < 2; ++pr)
#pragma unroll
      for (int r = 0; r < 4; ++r) cr[l][pr][r] = cinit[pr][r];

  __syncthreads();

  // ---- warm-up: REC(0,0) with t0 biases ----
  f32x4 accA[4], accB[4];
  REC4(0, HBUF(0), bA0, bB0)

  for (int t = 0; t < T; ++t) {
#pragma unroll
    for (int l = 0; l < 4; ++l) {
      barrier_lgkm();  // orders prev act-writes vs this segment's IN/pred reads
      // ---- IN: input-half MFMAs ((0,0) skipped: x0 folded into bA0/bB0) ----
      if (t + l != 0) {
        const ushort* hp = HBUF(l == 0 ? 3 : l - 1);
        IN4(l, hp)
      }
      // ---- pred (store-only): out[t-1] from h3(t-1), bo folded into acc init ----
      if (l == 0 && t > 0 && w < 4) {
        const ushort* h3 = HBUF(3);
        const int arow = w * 16 + c16;
        short8 p0 = *(const short8*)(h3 + arow * 72 + qs8);
        short8 p1 = *(const short8*)(h3 + arow * 72 + 32 + qs8);
        f32x4 P = {boc, boc, boc, boc};
        P = __builtin_amdgcn_mfma_f32_16x16x32_bf16(p0, wo0, P, 0, 0, 0);
        P = __builtin_amdgcn_mfma_f32_16x16x32_bf16(p1, wo1, P, 0, 0, 0);
        if (c16 < 3) {
#pragma unroll
          for (int r = 0; r < 4; ++r) {
            int rloc = w * 16 + q * 4 + r;
            out[(long)(row0 + rloc) * (3 * T) + (long)(t - 1) * 3 + c16] = P[r];
          }
        }
      }
      // ---- act: write h_l(t) IN PLACE into HBUF(l) ----
#pragma unroll
      for (int pr = 0; pr < 2; ++pr) {
        const int mtA = pr * 2, mtB = pr * 2 + 1;
        ushort* wb = HBUF(l) + (pr * 32 + hi16 + q * 4) * 72 + wcol;
#pragma unroll
        for (int r = 0; r < 4; ++r) {
          float ipk = pkmerge<0xC>(accA[mtA][r], accA[mtB][r]);
          float fpk = pkmerge<0x3>(accA[mtB][r], accA[mtA][r]);
          float gpk = pkmerge<0xC>(accB[mtA][r], accB[mtB][r]);
          float opk = pkmerge<0x3>(accB[mtB][r], accB[mtA][r]);
          ACT_ONE(ipk, fpk, gpk, opk, cr[l][pr][r], wb + r * 72)
        }
      }
      // ---- REC for next layer-step (reads a DIFFERENT buffer -> no barrier) ----
      if (l == 3) { REC4(0, HBUF(0), bA[0], bB[0]) }
      else if (l == 0) { REC4(1, HBUF(1), bA[1], bB[1]) }
      else if (l == 1) { REC4(2, HBUF(2), bA[2], bB[2]) }
      else { REC4(3, HBUF(3), bA[3], bB[3]) }
    }
  }
  // ---- final pred: out[T-1] from h3(T-1) ----
  barrier_lgkm();
  if (w < 4) {
    const ushort* h3 = HBUF(3);
    const int arow = w * 16 + c16;
    short8 p0 = *(const short8*)(h3 + arow * 72 + qs8);
    short8 p1 = *(const short8*)(h3 + arow * 72 + 32 + qs8);
    f32x4 P = {boc, boc, boc, boc};
    P = __builtin_amdgcn_mfma_f32_16x16x32_bf16(p0, wo0, P, 0, 0, 0);
    P = __builtin_amdgcn_mfma_f32_16x16x32_bf16(p1, wo1, P, 0, 0, 0);
    if (c16 < 3) {
#pragma unroll
      for (int r = 0; r < 4; ++r) {
        int rloc = w * 16 + q * 4 + r;
        out[(long)(row0 + rloc) * (3 * T) + (long)(T - 1) * 3 + c16] = P[r];
      }
    }
  }
}

extern "C" void kernel_launch(void* const* d_in, const int* in_sizes, int n_in,
                              void* d_out, int out_size, void* d_ws, size_t ws_size,
                              hipStream_t stream) {
  const float* conds = (const float*)d_in[0];
  const float* W1    = (const float*)d_in[1];
  const float* b1    = (const float*)d_in[2];
  const float* W2    = (const float*)d_in[3];
  const float* b2    = (const float*)d_in[4];
  const float* Wih0  = (const float*)d_in[5];
  const float* Wihr  = (const float*)d_in[6];
  const float* Whh   = (const float*)d_in[7];
  const float* bih   = (const float*)d_in[8];
  const float* bhh   = (const float*)d_in[9];
  const float* Wo    = (const float*)d_in[10];
  const float* bo    = (const float*)d_in[11];
  const int*   seqp  = (const int*)d_in[12];

  const int B = in_sizes[0] / 8;  // 65536

  ushort* wfrag = (ushort*)d_ws;             // 131072 shorts
  ushort* wofrag = wfrag + 131072;           // 1024 shorts
  float* bsum = (float*)(wofrag + 1024);     // 1024 floats
  float* bsum_t0 = bsum + 1024;              // 256 floats

  prep_kernel<<<521, 256, 0, stream>>>(Wih0, Wihr, Whh, bih, bhh, Wo, bo,
                                       wfrag, wofrag, bsum, bsum_t0);
  lstm_kernel<<<B / 64, 512, 0, stream>>>(conds, W1, b1, W2, b2, bo, seqp,
                                          wfrag, wofrag, bsum, bsum_t0, (float*)d_out);
}